// Round 1
// baseline (46.577 us; speedup 1.0000x reference)
//
#include <hip/hip_runtime.h>

// Masked Pearson correlation per row, summed over batch.
// pre, label: [B=32, L=128, N=8192] fp32.  out: [L=128] fp32.
// Memory-bound: 256 MiB read -> target ~43 us at 6.3 TB/s.

#define THRESH 0.001f

constexpr int B = 32;
constexpr int L = 128;
constexpr int N = 8192;
constexpr int BLOCK = 256;          // multiple of 64 (wave size)
constexpr int ITERS = N / 4 / BLOCK; // 8 float4 loads per input per thread

__global__ __launch_bounds__(BLOCK) void cc_row_kernel(const float* __restrict__ pre,
                                                       const float* __restrict__ label,
                                                       float* __restrict__ row_cc) {
    const int row = blockIdx.x;  // row = b*L + l, 0..4095
    const float4* p4 = reinterpret_cast<const float4*>(pre)   + (size_t)row * (N / 4);
    const float4* l4 = reinterpret_cast<const float4*>(label) + (size_t)row * (N / 4);

    float cnt = 0.f, sp = 0.f, sl = 0.f, spp = 0.f, sll = 0.f, spl = 0.f;

    #pragma unroll
    for (int i = 0; i < ITERS; ++i) {
        const int idx = threadIdx.x + i * BLOCK;   // coalesced: lane i -> consecutive float4
        const float4 p = p4[idx];
        const float4 l = l4[idx];
        const float pv[4] = {p.x, p.y, p.z, p.w};
        const float lv[4] = {l.x, l.y, l.z, l.w};
        #pragma unroll
        for (int j = 0; j < 4; ++j) {
            const float pj = pv[j];
            const float lj = lv[j];
            const float m = ((fabsf(pj) > THRESH) || (fabsf(lj) > THRESH)) ? 1.f : 0.f;
            const float pm = pj * m;
            const float lm = lj * m;
            cnt += m;
            sp  += pm;
            sl  += lm;
            spp += pm * pj;
            sll += lm * lj;
            spl += pm * lj;
        }
    }

    // Reduce 6 values across the 64-lane wave.
    #pragma unroll
    for (int off = 32; off > 0; off >>= 1) {
        cnt += __shfl_down(cnt, off);
        sp  += __shfl_down(sp,  off);
        sl  += __shfl_down(sl,  off);
        spp += __shfl_down(spp, off);
        sll += __shfl_down(sll, off);
        spl += __shfl_down(spl, off);
    }

    // Reduce across the 4 waves via LDS.
    __shared__ float red[BLOCK / 64][6];
    const int lane = threadIdx.x & 63;
    const int wave = threadIdx.x >> 6;
    if (lane == 0) {
        red[wave][0] = cnt; red[wave][1] = sp;  red[wave][2] = sl;
        red[wave][3] = spp; red[wave][4] = sll; red[wave][5] = spl;
    }
    __syncthreads();

    if (threadIdx.x == 0) {
        float c = 0.f, a = 0.f, b = 0.f, qp = 0.f, ql = 0.f, q = 0.f;
        #pragma unroll
        for (int w = 0; w < BLOCK / 64; ++w) {
            c  += red[w][0]; a  += red[w][1]; b  += red[w][2];
            qp += red[w][3]; ql += red[w][4]; q  += red[w][5];
        }
        // cov   = sum(pl*m) - sum(p*m)*sum(l*m)/cnt
        // var_p = sum(p^2*m) - sum(p*m)^2/cnt   (same for l)
        const float cov = q  - a * b / c;
        const float vp  = qp - a * a / c;
        const float vl  = ql - b * b / c;
        row_cc[row] = cov / sqrtf(vp * vl);
    }
}

// Sum cc over batch: out[l] = sum_b row_cc[b*L + l].  Deterministic (no atomics).
__global__ __launch_bounds__(L) void cc_sum_kernel(const float* __restrict__ row_cc,
                                                   float* __restrict__ out) {
    const int l = threadIdx.x;
    float s = 0.f;
    #pragma unroll
    for (int b = 0; b < B; ++b) s += row_cc[b * L + l];
    out[l] = s;
}

extern "C" void kernel_launch(void* const* d_in, const int* in_sizes, int n_in,
                              void* d_out, int out_size, void* d_ws, size_t ws_size,
                              hipStream_t stream) {
    const float* pre   = (const float*)d_in[0];
    const float* label = (const float*)d_in[1];
    float* out    = (float*)d_out;
    float* row_cc = (float*)d_ws;   // 4096 floats = 16 KiB scratch

    cc_row_kernel<<<B * L, BLOCK, 0, stream>>>(pre, label, row_cc);
    cc_sum_kernel<<<1, L, 0, stream>>>(row_cc, out);
}